// Round 20
// baseline (90.893 us; speedup 1.0000x reference)
//
#include <hip/hip_runtime.h>

// Conv2d 3x3, cin=4, cout=4, pad=1, stride=1 on [4,4096,4096] fp32.
//
// Round-20: MAX-TLP restructure of R18 (90.7 us best). Tile = 256px x
// 8 rows per 256-thread block; thread = 4px x 2rows x 4cout (32 acc).
// Wave w -> output rows y0+2w..2w+1; per ci stage 10 rows as 10 row-chunks
// (1024 B DMA each; waves own 3/3/2/2 -> per-wave counted vmcnt(3)/(2)).
// LDS = 2 x 10 x 256 x 4B = 20480 B EXACTLY -> 8 blocks/CU = 32 waves/CU
// (2x R18's 16; VGPR ~45 <= 64 keeps 8 waves/SIMD legal). Halo loads
// (32, wave-uniform via readfirstlane'd wave id) hoisted to s_loads at
// kernel start (R18's win). Unrolled 2-phase vmcnt-counted skeleton,
// XCD-bijective swizzle (grid 8192 = 16 strips x 512 row-blocks),
// nt stores. Lane-edge LDS indices clamped (OOB-safe, cndmask'd out).

#define IW 4096
#define IH 4096
constexpr long long HWsz = (long long)IH * IW;

typedef float v4f __attribute__((ext_vector_type(4)));

__device__ __forceinline__ void gload_lds16(const float* g, float* l) {
    __builtin_amdgcn_global_load_lds(
        (const __attribute__((address_space(1))) char*)g,
        (__attribute__((address_space(3))) char*)l, 16, 0, 0);
}

// stage one ci plane: 10 rows = 10 chunks (256 floats each);
// wave 0: rows 0-2, wave 1: rows 3-5, wave 2: rows 6-7, wave 3: rows 8-9
__device__ __forceinline__ void stage(const float* __restrict__ xin, int ci,
                                      float (*rbuf)[256], int y0, int X0,
                                      int w_u, int nw, int base, int l) {
    const float* plane = xin + (long long)ci * HWsz;
    #pragma unroll
    for (int k = 0; k < 3; ++k) {
        if (k < nw) {                            // wave-uniform guard
            const int r = base + k;              // staged row 0..9
            int yy = y0 - 1 + r;
            int yc = yy < 0 ? 0 : (yy >= IH ? IH - 1 : yy);  // clamp pad rows
            gload_lds16(plane + (long long)yc * IW + (X0 + 4 * l),
                        &rbuf[r][0]);
        }
    }
}

// compute one ci; wave w handles staged rows 2w..2w+3 -> out rows yw,yw+1
__device__ __forceinline__ void compute_ci(float acc[2][4][4],
                                           const float (*rbuf)[256],
                                           const float hl[4], const float hr[4],
                                           const float* __restrict__ wt,
                                           int ci, int y0, int w_u,
                                           int l, int iL, int iR) {
    #pragma unroll
    for (int dy = 0; dy < 4; ++dy) {
        const int r  = 2 * w_u + dy;             // staged row (wave-uniform)
        const int yy = y0 - 1 + r;               // global input row (uniform)
        if (yy >= 0 && yy < IH) {                // wave-uniform row skip
            const v4f a = *reinterpret_cast<const v4f*>(&rbuf[r][4 * l]);
            const float L = (l == 0)  ? hl[dy] : rbuf[r][iL];
            const float R = (l == 63) ? hr[dy] : rbuf[r][iR];
            float vv[6] = {L, a.x, a.y, a.z, a.w, R};
            #pragma unroll
            for (int rk = 0; rk < 3; ++rk) {
                const int o = dy - rk;           // output row offset (0..1)
                if (o >= 0 && o < 2) {
                    #pragma unroll
                    for (int co = 0; co < 4; ++co) {
                        #pragma unroll
                        for (int kx = 0; kx < 3; ++kx) {
                            const float w = wt[((co * 4 + ci) * 3 + rk) * 3 + kx];
                            #pragma unroll
                            for (int p = 0; p < 4; ++p)
                                acc[o][co][p] = fmaf(w, vv[p + kx], acc[o][co][p]);
                        }
                    }
                }
            }
        }
    }
}

__global__ __launch_bounds__(256) void conv3x3_kernel(
    const float* __restrict__ xin,   // [4][4096][4096]
    const float* __restrict__ wt,    // [4][4][3][3]
    float* __restrict__ out)         // [4][4096][4096]
{
    __shared__ __align__(16) float rows[2][10][256];   // 20480 B exactly

    // grid 8192 = 512 row-blocks x 16 x-strips; bijective XCD swizzle:
    // XCD x owns swz [x*1024,(x+1)*1024) -> 64 row-blocks (512 rows) band
    const int bid = blockIdx.x;
    const int swz = (bid & 7) * 1024 + (bid >> 3);
    const int rowblk = swz >> 4;                  // 0..511
    const int xs     = swz & 15;                  // 0..15
    const int y0     = rowblk << 3;               // 8 output rows
    const int X0     = xs << 8;                   // 256-px strip
    const int t      = (int)threadIdx.x;
    const int l      = t & 63;
    const int w_u    = __builtin_amdgcn_readfirstlane(t >> 6);  // wave 0..3
    const int yw     = y0 + 2 * w_u;              // wave's first output row
    const bool xlo   = (X0 == 0);
    const bool xhi   = (X0 + 256 == IW);
    // clamped lane-edge LDS indices (in-range garbage, cndmask'd out)
    const int iL = (l == 0)  ? 0   : 4 * l - 1;
    const int iR = (l == 63) ? 0   : 4 * l + 4;
    // stage ownership: waves 0,1 -> 3 chunks; waves 2,3 -> 2 chunks
    const int nw   = (w_u < 2) ? 3 : 2;
    const int base = (w_u < 2) ? 3 * w_u : 6 + 2 * (w_u - 2);

    // ---- hoisted halo loads: wave-uniform -> s_loads, latency hidden ----
    float hl[4][4], hr[4][4];                     // [ci][dy]
    #pragma unroll
    for (int ci = 0; ci < 4; ++ci) {
        const float* plane = xin + (long long)ci * HWsz;
        #pragma unroll
        for (int dy = 0; dy < 4; ++dy) {
            const int yy = yw - 1 + dy;
            const bool vrow = (yy >= 0 && yy < IH);
            const long long rb = (long long)(vrow ? yy : 0) * IW;
            hl[ci][dy] = (vrow && !xlo) ? plane[rb + X0 - 1]   : 0.f;
            hr[ci][dy] = (vrow && !xhi) ? plane[rb + X0 + 256] : 0.f;
        }
    }

    float acc[2][4][4];                           // [orow][cout][px]
    #pragma unroll
    for (int o = 0; o < 2; ++o)
        #pragma unroll
        for (int co = 0; co < 4; ++co)
            #pragma unroll
            for (int p = 0; p < 4; ++p) acc[o][co][p] = 0.f;

    // ---- fully unrolled 2-phase pipeline, per-wave counted vmcnt ----
    stage(xin, 0, rows[0], y0, X0, w_u, nw, base, l);   // prologue

    // ci = 0
    stage(xin, 1, rows[1], y0, X0, w_u, nw, base, l);
    if (w_u < 2) asm volatile("s_waitcnt vmcnt(3)" ::: "memory");
    else         asm volatile("s_waitcnt vmcnt(2)" ::: "memory");
    asm volatile("s_barrier" ::: "memory");
    compute_ci(acc, rows[0], hl[0], hr[0], wt, 0, y0, w_u, l, iL, iR);
    asm volatile("s_barrier" ::: "memory");
    // ci = 1
    stage(xin, 2, rows[0], y0, X0, w_u, nw, base, l);
    if (w_u < 2) asm volatile("s_waitcnt vmcnt(3)" ::: "memory");
    else         asm volatile("s_waitcnt vmcnt(2)" ::: "memory");
    asm volatile("s_barrier" ::: "memory");
    compute_ci(acc, rows[1], hl[1], hr[1], wt, 1, y0, w_u, l, iL, iR);
    asm volatile("s_barrier" ::: "memory");
    // ci = 2
    stage(xin, 3, rows[1], y0, X0, w_u, nw, base, l);
    if (w_u < 2) asm volatile("s_waitcnt vmcnt(3)" ::: "memory");
    else         asm volatile("s_waitcnt vmcnt(2)" ::: "memory");
    asm volatile("s_barrier" ::: "memory");
    compute_ci(acc, rows[0], hl[2], hr[2], wt, 2, y0, w_u, l, iL, iR);
    asm volatile("s_barrier" ::: "memory");
    // ci = 3
    asm volatile("s_waitcnt vmcnt(0)\n\ts_barrier" ::: "memory");
    compute_ci(acc, rows[1], hl[3], hr[3], wt, 3, y0, w_u, l, iL, iR);

    // ---- store: 2 rows x 4 cout nt dwordx4 ----
    const int x0g = X0 + 4 * l;
    #pragma unroll
    for (int o = 0; o < 2; ++o) {
        const long long obase = (long long)(yw + o) * IW + x0g;
        #pragma unroll
        for (int co = 0; co < 4; ++co) {
            v4f ov;
            ov.x = acc[o][co][0]; ov.y = acc[o][co][1];
            ov.z = acc[o][co][2]; ov.w = acc[o][co][3];
            __builtin_nontemporal_store(ov,
                reinterpret_cast<v4f*>(out + co * HWsz + obase));
        }
    }
}

extern "C" void kernel_launch(void* const* d_in, const int* in_sizes, int n_in,
                              void* d_out, int out_size, void* d_ws, size_t ws_size,
                              hipStream_t stream) {
    const float* xin = (const float*)d_in[0];
    const float* wt  = (const float*)d_in[1];
    float* out       = (float*)d_out;

    dim3 grid(8192), block(256);
    hipLaunchKernelGGL(conv3x3_kernel, grid, block, 0, stream, xin, wt, out);
}

// Round 22
// 87.487 us; speedup vs baseline: 1.0389x; 1.0389x over previous
//
#include <hip/hip_runtime.h>

// Conv2d 3x3, cin=4, cout=4, pad=1, stride=1 on [4,4096,4096] fp32.
//
// Round-22: DEPTH-2 prefetch at unchanged occupancy. Tile = 512px x 4 rows
// (grid 8192); thread = 4px x 2rows x 4cout (32 acc); wave w -> row-pair
// p=w>>1, stages chunks 3w..3w+2 (3 DMAs/stage). THREE LDS buffers
// (3 x 6 x 512 x 4B = 36864 B < 40960 -> still 4 blocks/CU = 16 waves/CU),
// stage(ci+2) issued 2 compute-phases ahead; steady wait vmcnt(6) keeps
// 6 DMAs in flight (never drains mid-loop). Halo columns hoisted to
// wave-uniform loads at kernel start (R18 win). nt BUILTIN stores only
// (R21 lesson: sc1-scoped stores break L2 coherence for validation reads).

#define IW 4096
#define IH 4096
constexpr long long HWsz = (long long)IH * IW;

typedef float v4f __attribute__((ext_vector_type(4)));

__device__ __forceinline__ void gload_lds16(const float* g, float* l) {
    __builtin_amdgcn_global_load_lds(
        (const __attribute__((address_space(1))) char*)g,
        (__attribute__((address_space(3))) char*)l, 16, 0, 0);
}

// stage one ci plane into buf: 6 rows x 2 half-strips = 12 chunks;
// wave w owns chunks 3w..3w+2 (3 DMAs, vmcnt-counted per wave)
__device__ __forceinline__ void stage(const float* __restrict__ xin, int ci,
                                      float (*rbuf)[512], int y0, int X0,
                                      int w, int l) {
    const float* plane = xin + (long long)ci * HWsz;
    #pragma unroll
    for (int k = 0; k < 3; ++k) {
        const int c = 3 * w + k;                 // chunk id 0..11 (uniform)
        const int r = c >> 1;                    // staged row 0..5
        const int h = c & 1;                     // half-strip
        int yy = y0 - 1 + r;
        int yc = yy < 0 ? 0 : (yy >= IH ? IH - 1 : yy);   // clamp: pad rows
        gload_lds16(plane + (long long)yc * IW + (X0 + 256 * h + 4 * l),
                    &rbuf[r][256 * h]);
    }
}

// compute one ci; wave pair p reads staged rows 2p..2p+3 -> out rows yw,yw+1
__device__ __forceinline__ void compute_ci(float acc[2][4][4],
                                           const float (*rbuf)[512],
                                           const float hl[4], const float hr[4],
                                           const float* __restrict__ wt,
                                           int ci, int y0, int p_u,
                                           int txs, int iL, int iR) {
    #pragma unroll
    for (int dy = 0; dy < 4; ++dy) {
        const int r  = 2 * p_u + dy;             // staged row (wave-uniform)
        const int yy = y0 - 1 + r;               // global input row (uniform)
        if (yy >= 0 && yy < IH) {                // wave-uniform row skip
            const v4f a = *reinterpret_cast<const v4f*>(&rbuf[r][4 * txs]);
            const float L = (txs == 0)   ? hl[dy] : rbuf[r][iL];
            const float R = (txs == 127) ? hr[dy] : rbuf[r][iR];
            float vv[6] = {L, a.x, a.y, a.z, a.w, R};
            #pragma unroll
            for (int rk = 0; rk < 3; ++rk) {
                const int o = dy - rk;           // output row offset (0..1)
                if (o >= 0 && o < 2) {
                    #pragma unroll
                    for (int co = 0; co < 4; ++co) {
                        #pragma unroll
                        for (int kx = 0; kx < 3; ++kx) {
                            const float w = wt[((co * 4 + ci) * 3 + rk) * 3 + kx];
                            #pragma unroll
                            for (int p = 0; p < 4; ++p)
                                acc[o][co][p] = fmaf(w, vv[p + kx], acc[o][co][p]);
                        }
                    }
                }
            }
        }
    }
}

__global__ __launch_bounds__(256) void conv3x3_kernel(
    const float* __restrict__ xin,   // [4][4096][4096]
    const float* __restrict__ wt,    // [4][4][3][3]
    float* __restrict__ out)         // [4][4096][4096]
{
    __shared__ __align__(16) float rows[3][6][512];    // 36864 B (<40960)

    // grid 8192 = 1024 row-blocks x 8 x-strips; bijective XCD swizzle:
    // XCD x owns swz [x*1024,(x+1)*1024) -> 128 row-blocks = 512-row band
    const int bid = blockIdx.x;
    const int swz = (bid & 7) * 1024 + (bid >> 3);
    const int rowblk = swz >> 3;                  // 0..1023
    const int xs     = swz & 7;                   // 0..7
    const int y0     = rowblk << 2;               // 4 output rows
    const int X0     = xs << 9;                   // 512-px strip
    const int t      = (int)threadIdx.x;
    const int w      = t >> 6, l = t & 63;
    const int txs    = t & 127;                   // px index within pair
    const int p_u    = __builtin_amdgcn_readfirstlane(t >> 7);  // pair 0/1
    const int yw     = y0 + 2 * p_u;              // pair's first output row
    // clamped lane-edge LDS indices (in-range garbage, cndmask'd out)
    const int iL = (txs == 0)   ? 0 : 4 * txs - 1;
    const int iR = (txs == 127) ? 0 : 4 * txs + 4;

    // ---- hoisted halo loads: wave-uniform -> issued up front, latency
    //      hidden under the prologue DMA waits ----
    float hl[4][4], hr[4][4];                     // [ci][dy]
    #pragma unroll
    for (int ci = 0; ci < 4; ++ci) {
        const float* plane = xin + (long long)ci * HWsz;
        #pragma unroll
        for (int dy = 0; dy < 4; ++dy) {
            const int yy = yw - 1 + dy;
            const bool vrow = (yy >= 0 && yy < IH);
            const long long rb = (long long)(vrow ? yy : 0) * IW;
            hl[ci][dy] = (vrow && X0 > 0)        ? plane[rb + X0 - 1]   : 0.f;
            hr[ci][dy] = (vrow && X0 + 512 < IW) ? plane[rb + X0 + 512] : 0.f;
        }
    }

    float acc[2][4][4];                           // [orow][cout][px]
    #pragma unroll
    for (int o = 0; o < 2; ++o)
        #pragma unroll
        for (int co = 0; co < 4; ++co)
            #pragma unroll
            for (int p = 0; p < 4; ++p) acc[o][co][p] = 0.f;

    // ---- depth-2 pipeline, fully unrolled ----
    stage(xin, 0, rows[0], y0, X0, w, l);         // prologue
    stage(xin, 1, rows[1], y0, X0, w, l);

    // ci = 0: issue ci=2, wait ci=0 (6 newest stay in flight)
    stage(xin, 2, rows[2], y0, X0, w, l);
    asm volatile("s_waitcnt vmcnt(6)\n\ts_barrier" ::: "memory");
    compute_ci(acc, rows[0], hl[0], hr[0], wt, 0, y0, p_u, txs, iL, iR);
    asm volatile("s_barrier" ::: "memory");       // buf0 readers done
    // ci = 1: issue ci=3 into buf0, wait ci=1
    stage(xin, 3, rows[0], y0, X0, w, l);
    asm volatile("s_waitcnt vmcnt(6)\n\ts_barrier" ::: "memory");
    compute_ci(acc, rows[1], hl[1], hr[1], wt, 1, y0, p_u, txs, iL, iR);
    // ci = 2: wait ci=2 (ci=3's 3 DMAs stay in flight)
    asm volatile("s_waitcnt vmcnt(3)\n\ts_barrier" ::: "memory");
    compute_ci(acc, rows[2], hl[2], hr[2], wt, 2, y0, p_u, txs, iL, iR);
    // ci = 3: drain
    asm volatile("s_waitcnt vmcnt(0)\n\ts_barrier" ::: "memory");
    compute_ci(acc, rows[0], hl[3], hr[3], wt, 3, y0, p_u, txs, iL, iR);

    // ---- store: 2 rows x 4 cout nt dwordx4 ----
    const int x0g = X0 + 4 * txs;
    #pragma unroll
    for (int o = 0; o < 2; ++o) {
        const long long obase = (long long)(yw + o) * IW + x0g;
        #pragma unroll
        for (int co = 0; co < 4; ++co) {
            v4f ov;
            ov.x = acc[o][co][0]; ov.y = acc[o][co][1];
            ov.z = acc[o][co][2]; ov.w = acc[o][co][3];
            __builtin_nontemporal_store(ov,
                reinterpret_cast<v4f*>(out + co * HWsz + obase));
        }
    }
}

extern "C" void kernel_launch(void* const* d_in, const int* in_sizes, int n_in,
                              void* d_out, int out_size, void* d_ws, size_t ws_size,
                              hipStream_t stream) {
    const float* xin = (const float*)d_in[0];
    const float* wt  = (const float*)d_in[1];
    float* out       = (float*)d_out;

    dim3 grid(8192), block(256);
    hipLaunchKernelGGL(conv3x3_kernel, grid, block, 0, stream, xin, wt, out);
}